// Round 4
// baseline (6050.060 us; speedup 1.0000x reference)
//
#include <hip/hip_runtime.h>

#define NEX 65536
#define NT 512
#define EPB 4          // examples per block, one (e,m) per thread
#define HHC (1.0f/3.0f)

// ---- d_ws layout (bytes), all f32 ----
// WT: 3 layers transposed Ws, each [144 rows k][132 cols m] (cols 128..131 = 0)
//     wt[i][k][m] = Ws[i][m][k]
// W0T: [32][132], w0t[k][m] = W0[m][k]
constexpr int WS_WT  = 0;                    // 3*144*132*4 = 228096
constexpr int WS_W0T = 3*144*132*4;          // 228096
constexpr int WS_K2  = WS_W0T + 32*132*4;    // 244992
constexpr int WS_SA  = WS_K2 + 128*4;        // 245504
constexpr int WS_TRA = WS_SA + 256*4;        // 246528

// ---- LDS layout (bytes), all f32 ----
constexpr int SM_WT  = 0;                    // one layer [144][132] f32 = 76032
constexpr int SM_W0T = 76032;                // [32][132] f32 = 16896
constexpr int SM_TP  = SM_W0T + 16896;       // 92928: tanh(pre) f32 [3][4][128] = 6144
constexpr int SM_JAC = SM_TP + 6144;         // 99072: f32 [4][128][20] = 40960
constexpr int SM_U   = SM_JAC + 40960;       // 140032: [4][128]
constexpr int SM_Z2  = SM_U  + 2048;         // 142080
constexpr int SM_Z3  = SM_Z2 + 2048;         // 144128
constexpr int SM_XC  = SM_Z3 + 2048;         // 146176: [4][32] (x | ctx)
constexpr int SM_K2  = SM_XC + 512;          // 146688
constexpr int SM_B0  = SM_K2 + 512;          // 147200
constexpr int SM_BS  = SM_B0 + 512;          // 147712: [3][128]
constexpr int SM_WW  = SM_BS + 1536;         // 149248
constexpr int SM_CW  = SM_WW + 512;          // 149760
constexpr int SM_SA  = SM_CW + 64;           // 149824: [16][16]
constexpr int SM_TRHP= SM_SA + 1024;         // 150848: [4][2]
constexpr int SM_JP  = SM_TRHP + 32;         // 150880: [8]
constexpr int SM_TRA = SM_JP + 32;           // 150912
constexpr int SM_TOTAL = SM_TRA + 16;        // 150928 bytes < 160 KiB

__device__ __forceinline__ float adtanh(float v){
  float a = fabsf(v);
  return a + log1pf(expf(-2.0f * a));
}

__global__ void phi_prep(const float* __restrict__ W0, const float* __restrict__ Ws,
                         const float* __restrict__ A, char* __restrict__ ws){
  const int tid = threadIdx.x;
  float* wt  = (float*)(ws + WS_WT);
  float* w0t = (float*)(ws + WS_W0T);
  float* k2  = (float*)(ws + WS_K2);
  float* sa  = (float*)(ws + WS_SA);
  float* trA = (float*)(ws + WS_TRA);
  for (int idx = tid; idx < 3*144*132; idx += NT){
    int i = idx / (144*132), r = idx % (144*132);
    int k = r / 132, mm = r % 132;
    wt[idx] = (mm < 128) ? Ws[i*128*144 + mm*144 + k] : 0.0f;
  }
  for (int idx = tid; idx < 32*132; idx += NT){
    int k = idx / 132, mm = idx % 132;
    w0t[idx] = (mm < 128) ? W0[mm*32 + k] : 0.0f;
  }
  if (tid < 128){
    float s = 0.0f;
    for (int d = 0; d < 15; ++d){ float w = W0[tid*32 + d]; s += w*w; }
    k2[tid] = s;
  }
  if (tid >= 256){   // symA = A^T A, 16x16
    int t = tid - 256; int i = t >> 4, j = t & 15;
    float s = 0.0f;
    for (int r = 0; r < 10; ++r) s += A[r*16 + i] * A[r*16 + j];
    sa[i*16 + j] = s;
  }
  if (tid == 255){
    float s = 0.0f;
    for (int d = 0; d < 15; ++d)
      for (int r = 0; r < 10; ++r){ float a = A[r*16 + d]; s += a*a; }
    trA[0] = s;
  }
}

__global__ void __launch_bounds__(NT, 1)
phi_main(const float* __restrict__ x, const float* __restrict__ ctx,
         const float* __restrict__ b0, const float* __restrict__ bs,
         const float* __restrict__ cw, const float* __restrict__ ww,
         const char* __restrict__ ws, float* __restrict__ out){
  extern __shared__ char smem[];
  float* sWT  = (float*)(smem + SM_WT);
  float* sW0T = (float*)(smem + SM_W0T);
  float* sTP  = (float*)(smem + SM_TP);
  float* sJAC = (float*)(smem + SM_JAC);
  float* sU   = (float*)(smem + SM_U);
  float* sZ2  = (float*)(smem + SM_Z2);
  float* sZ3  = (float*)(smem + SM_Z3);
  float* sXC  = (float*)(smem + SM_XC);
  float* sK2  = (float*)(smem + SM_K2);
  float* sB0  = (float*)(smem + SM_B0);
  float* sBS  = (float*)(smem + SM_BS);
  float* sWW  = (float*)(smem + SM_WW);
  float* sCW  = (float*)(smem + SM_CW);
  float* sSA  = (float*)(smem + SM_SA);
  float* sTRHP= (float*)(smem + SM_TRHP);
  float* sJP  = (float*)(smem + SM_JP);
  float* sTRA = (float*)(smem + SM_TRA);

  const int tid = threadIdx.x;
  const int ebase = blockIdx.x * EPB;

  // ---- stage W0T + small constants + inputs ----
  {
    const uint4* src = (const uint4*)(ws + WS_W0T);
    uint4* dst = (uint4*)sW0T;
    for (int idx = tid; idx < 1056; idx += NT) dst[idx] = src[idx];  // 16896 B
    if (tid < 128){
      sK2[tid] = ((const float*)(ws + WS_K2))[tid];
      sB0[tid] = b0[tid];
      sWW[tid] = ww[tid];
    }
    if (tid >= 128 && tid < 144) sCW[tid-128] = cw[tid-128];
    if (tid == 144) sTRA[0] = ((const float*)(ws + WS_TRA))[0];
    if (tid < 384) sBS[tid] = bs[tid];
    if (tid >= 256) sSA[tid-256] = ((const float*)(ws + WS_SA))[tid-256];
    if (tid < 128){
      int e = tid >> 5, k = tid & 31;
      int n = ebase + e;
      sXC[e*32 + k] = (k < 16) ? x[n*16 + k] : ctx[n*16 + (k-16)];
    }
  }
  __syncthreads();

  const int e = tid >> 7;          // 0..3
  const int m = tid & 127;

  // ---- opening ----
  float acc = sB0[m];
  #pragma unroll
  for (int k = 0; k < 32; ++k)
    acc += sW0T[k*132 + m] * sXC[e*32 + k];
  const float to = tanhf(acc);
  sU[e*128 + m] = adtanh(acc);
  __syncthreads();

  // ---- forward layers ----
  for (int i0 = 0; i0 < 3; ++i0){
    {
      const uint4* src = (const uint4*)(ws + WS_WT + i0*144*132*4);
      uint4* dst = (uint4*)sWT;
      for (int idx = tid; idx < 4752; idx += NT) dst[idx] = src[idx];
    }
    __syncthreads();
    float p = sBS[i0*128 + m];
    for (int k = 0; k < 128; ++k)
      p += sWT[k*132 + m] * sU[e*128 + k];
    #pragma unroll
    for (int k = 0; k < 16; ++k)
      p += sWT[(128+k)*132 + m] * sXC[e*32 + 16 + k];
    __syncthreads();   // all reads of sU done before update
    sU[e*128 + m] += HHC * adtanh(p);
    sTP[(i0*4 + e)*128 + m] = tanhf(p);
    __syncthreads();
  }

  // ---- z3 (sWT currently = WT layer 2) ----
  float zz = 0.0f;
  for (int a = 0; a < 128; ++a)
    zz += sWT[m*132 + a] * sTP[(8 + e)*128 + a] * sWW[a];
  sZ3[e*128 + m] = sWW[m] + HHC*zz;
  __syncthreads();

  // ---- z2 (stage WT layer 1) ----
  {
    const uint4* src = (const uint4*)(ws + WS_WT + 1*144*132*4);
    uint4* dst = (uint4*)sWT;
    for (int idx = tid; idx < 4752; idx += NT) dst[idx] = src[idx];
  }
  __syncthreads();
  zz = 0.0f;
  for (int a = 0; a < 128; ++a)
    zz += sWT[m*132 + a] * sTP[(4 + e)*128 + a] * sZ3[e*128 + a];
  sZ2[e*128 + m] = sZ3[e*128 + m] + HHC*zz;
  __syncthreads();

  // ---- z1 (stage WT layer 0) ----
  {
    const uint4* src = (const uint4*)(ws + WS_WT + 0);
    uint4* dst = (uint4*)sWT;
    for (int idx = tid; idx < 4752; idx += NT) dst[idx] = src[idx];
  }
  __syncthreads();
  zz = 0.0f;
  for (int a = 0; a < 128; ++a)
    zz += sWT[m*132 + a] * sTP[e*128 + a] * sZ2[e*128 + a];
  const float z1 = sZ2[e*128 + m] + HHC*zz;
  const float s20 = (1.0f - to*to) * z1 * sK2[m];
  sJAC[(e*128 + m)*20] = to * z1;    // s1 scratch in jac col 0
  __syncthreads();

  // ---- grad output ----
  if (tid < 64){
    int ge = tid >> 4, gd = tid & 15;
    float g = sCW[gd];
    #pragma unroll
    for (int j = 0; j < 16; ++j) g += sSA[gd*16 + j] * sXC[ge*32 + j];
    for (int mm = 0; mm < 128; ++mm)
      g += sW0T[gd*132 + mm] * sJAC[(ge*128 + mm)*20];
    out[(size_t)(ebase + ge)*16 + gd] = g;
  }
  // ---- trH z1-part reduction (wave w covers half of example w>>1) ----
  {
    float r = s20;
    #pragma unroll
    for (int off = 32; off >= 1; off >>= 1) r += __shfl_xor(r, off, 64);
    if ((tid & 63) == 0){
      int w = tid >> 6;
      sTRHP[(w >> 1)*2 + (w & 1)] = r;
    }
  }
  __syncthreads();

  // ---- Jac init ----
  #pragma unroll
  for (int d = 0; d < 20; ++d)
    sJAC[(e*128 + m)*20 + d] = ((d < 15) ? sW0T[d*132 + m] : 0.0f) * to;
  __syncthreads();

  // ---- Jac propagation (hot loop): 2 waves per example ----
  const int w  = tid >> 6;         // 0..7
  const int je = w >> 1;           // 0..3
  const int a  = (w & 1)*64 + (tid & 63);   // row 0..127
  const float* jb = sJAC + je*2560;
  float trh = 0.0f;
  for (int i0 = 0; i0 < 3; ++i0){
    if (i0 > 0){
      const uint4* src = (const uint4*)(ws + WS_WT + i0*144*132*4);
      uint4* dst = (uint4*)sWT;
      for (int idx = tid; idx < 4752; idx += NT) dst[idx] = src[idx];
      __syncthreads();
    }
    float kj[16];
    #pragma unroll
    for (int d = 0; d < 16; ++d) kj[d] = 0.0f;
    #pragma unroll 4
    for (int b = 0; b < 128; ++b){
      float jv[16];
      { float4 t = *(const float4*)(jb + b*20 + 0);  jv[0]=t.x; jv[1]=t.y; jv[2]=t.z; jv[3]=t.w; }
      { float4 t = *(const float4*)(jb + b*20 + 4);  jv[4]=t.x; jv[5]=t.y; jv[6]=t.z; jv[7]=t.w; }
      { float4 t = *(const float4*)(jb + b*20 + 8);  jv[8]=t.x; jv[9]=t.y; jv[10]=t.z; jv[11]=t.w; }
      { float4 t = *(const float4*)(jb + b*20 + 12); jv[12]=t.x; jv[13]=t.y; jv[14]=t.z; jv[15]=t.w; }
      float wv = sWT[b*132 + a];
      #pragma unroll
      for (int d = 0; d < 16; ++d) kj[d] += wv*jv[d];
    }
    float term;
    if (i0 == 0)      term = sZ2[je*128 + a];
    else if (i0 == 1) term = sZ3[je*128 + a];
    else              term = sWW[a];
    float tp = sTP[(i0*4 + je)*128 + a];
    float q = 0.0f;
    #pragma unroll
    for (int d = 0; d < 16; ++d) q += kj[d]*kj[d];
    float ss = (1.0f - tp*tp)*term*q;
    #pragma unroll
    for (int off = 32; off >= 1; off >>= 1) ss += __shfl_xor(ss, off, 64);
    trh += HHC * ss;
    __syncthreads();   // all jac reads done before update
    #pragma unroll
    for (int d = 0; d < 16; ++d)
      sJAC[(je*128 + a)*20 + d] += HHC*tp*kj[d];
    __syncthreads();
  }
  if ((tid & 63) == 0) sJP[w] = trh;
  __syncthreads();
  if (tid < 4){
    out[(size_t)NEX*16 + ebase + tid] =
      sTRHP[tid*2] + sTRHP[tid*2+1] + sJP[tid*2] + sJP[tid*2+1] + sTRA[0];
  }
}

extern "C" void kernel_launch(void* const* d_in, const int* in_sizes, int n_in,
                              void* d_out, int out_size, void* d_ws, size_t ws_size,
                              hipStream_t stream){
  const float* x   = (const float*)d_in[0];
  const float* ctx = (const float*)d_in[1];
  const float* W0  = (const float*)d_in[2];
  const float* b0  = (const float*)d_in[3];
  const float* Ws  = (const float*)d_in[4];
  const float* bs  = (const float*)d_in[5];
  const float* A   = (const float*)d_in[6];
  const float* cw  = (const float*)d_in[7];
  const float* ww  = (const float*)d_in[8];
  float* out = (float*)d_out;
  char* ws = (char*)d_ws;

  (void)in_sizes; (void)n_in; (void)out_size; (void)ws_size;
  hipFuncSetAttribute((const void*)phi_main,
                      hipFuncAttributeMaxDynamicSharedMemorySize, SM_TOTAL);
  phi_prep<<<1, NT, 0, stream>>>(W0, Ws, A, ws);
  phi_main<<<NEX/EPB, NT, SM_TOTAL, stream>>>(x, ctx, b0, bs, cw, ww, ws, out);
}

// Round 7
// 2660.650 us; speedup vs baseline: 2.2739x; 2.2739x over previous
//
#include <hip/hip_runtime.h>

#define NEX 65536
#define NT 512
#define EPB 4          // examples per block, one (e,m) per thread
#define HHC (1.0f/3.0f)

// ---- d_ws layout (bytes), all f32 ----
// WT: 3 layers transposed Ws, each [144 rows k][132 cols m] (cols 128..131 = 0)
//     wt[i][k][m] = Ws[i][m][k]   (coalesced for fwd + Jac loops)
// W0T: [32][132], w0t[k][m] = W0[m][k]
constexpr int WS_WT  = 0;                    // 3*144*132*4 = 228096
constexpr int WS_W0T = 3*144*132*4;          // 228096
constexpr int WS_K2  = WS_W0T + 32*132*4;    // 244992
constexpr int WS_SA  = WS_K2 + 128*4;        // 245504
constexpr int WS_TRA = WS_SA + 256*4;        // 246528

// ---- LDS layout (bytes), all f32 — weights NOT staged (L2-resident) ----
constexpr int SM_TP  = 0;                    // tanh(pre) [3][4][128] = 6144
constexpr int SM_JAC = 6144;                 // [4][128][20] = 40960
constexpr int SM_U   = 47104;                // [4][128]
constexpr int SM_Z2  = 49152;
constexpr int SM_Z3  = 51200;
constexpr int SM_XC  = 53248;                // [4][32] (x | ctx)
constexpr int SM_K2  = 53760;
constexpr int SM_B0  = 54272;
constexpr int SM_BS  = 54784;                // [3][128]
constexpr int SM_WW  = 56320;
constexpr int SM_CW  = 56832;
constexpr int SM_SA  = 56896;                // [16][16]
constexpr int SM_TRHP= 57920;                // [4][2]
constexpr int SM_JP  = 57952;                // [8]
constexpr int SM_TRA = 57984;
constexpr int SM_TOTAL = 58000;              // < 80 KB -> 2 blocks/CU

__device__ __forceinline__ float adtanh(float v){
  float a = fabsf(v);
  return a + log1pf(expf(-2.0f * a));
}

__global__ void phi_prep(const float* __restrict__ W0, const float* __restrict__ Ws,
                         const float* __restrict__ A, char* __restrict__ ws){
  const int tid = threadIdx.x;
  float* wt  = (float*)(ws + WS_WT);
  float* w0t = (float*)(ws + WS_W0T);
  float* k2  = (float*)(ws + WS_K2);
  float* sa  = (float*)(ws + WS_SA);
  float* trA = (float*)(ws + WS_TRA);
  for (int idx = tid; idx < 3*144*132; idx += NT){
    int i = idx / (144*132), r = idx % (144*132);
    int k = r / 132, mm = r % 132;
    wt[idx] = (mm < 128) ? Ws[i*128*144 + mm*144 + k] : 0.0f;
  }
  for (int idx = tid; idx < 32*132; idx += NT){
    int k = idx / 132, mm = idx % 132;
    w0t[idx] = (mm < 128) ? W0[mm*32 + k] : 0.0f;
  }
  if (tid < 128){
    float s = 0.0f;
    for (int d = 0; d < 15; ++d){ float w = W0[tid*32 + d]; s += w*w; }
    k2[tid] = s;
  }
  if (tid >= 256){   // symA = A^T A, 16x16
    int t = tid - 256; int i = t >> 4, j = t & 15;
    float s = 0.0f;
    for (int r = 0; r < 10; ++r) s += A[r*16 + i] * A[r*16 + j];
    sa[i*16 + j] = s;
  }
  if (tid == 255){
    float s = 0.0f;
    for (int d = 0; d < 15; ++d)
      for (int r = 0; r < 10; ++r){ float a = A[r*16 + d]; s += a*a; }
    trA[0] = s;
  }
}

__global__ void __launch_bounds__(NT, 4)   // 4 waves/SIMD -> 2 blocks/CU
phi_main(const float* __restrict__ x, const float* __restrict__ ctx,
         const float* __restrict__ W0g, const float* __restrict__ b0,
         const float* __restrict__ Wsg, const float* __restrict__ bs,
         const float* __restrict__ cw, const float* __restrict__ ww,
         const char* __restrict__ ws, float* __restrict__ out){
  extern __shared__ char smem[];
  float* sTP  = (float*)(smem + SM_TP);
  float* sJAC = (float*)(smem + SM_JAC);
  float* sU   = (float*)(smem + SM_U);
  float* sZ2  = (float*)(smem + SM_Z2);
  float* sZ3  = (float*)(smem + SM_Z3);
  float* sXC  = (float*)(smem + SM_XC);
  float* sK2  = (float*)(smem + SM_K2);
  float* sB0  = (float*)(smem + SM_B0);
  float* sBS  = (float*)(smem + SM_BS);
  float* sWW  = (float*)(smem + SM_WW);
  float* sCW  = (float*)(smem + SM_CW);
  float* sSA  = (float*)(smem + SM_SA);
  float* sTRHP= (float*)(smem + SM_TRHP);
  float* sJP  = (float*)(smem + SM_JP);
  float* sTRA = (float*)(smem + SM_TRA);

  const float* gWT  = (const float*)(ws + WS_WT);
  const float* gW0T = (const float*)(ws + WS_W0T);

  const int tid = threadIdx.x;
  const int ebase = blockIdx.x * EPB;

  // ---- stage small constants + inputs ----
  {
    if (tid < 128){
      sK2[tid] = ((const float*)(ws + WS_K2))[tid];
      sB0[tid] = b0[tid];
      sWW[tid] = ww[tid];
    }
    if (tid >= 128 && tid < 144) sCW[tid-128] = cw[tid-128];
    if (tid == 144) sTRA[0] = ((const float*)(ws + WS_TRA))[0];
    if (tid < 384) sBS[tid] = bs[tid];
    if (tid >= 256) sSA[tid-256] = ((const float*)(ws + WS_SA))[tid-256];
    if (tid < 128){
      int e = tid >> 5, k = tid & 31;
      int n = ebase + e;
      sXC[e*32 + k] = (k < 16) ? x[n*16 + k] : ctx[n*16 + (k-16)];
    }
  }
  __syncthreads();

  const int e = tid >> 7;          // 0..3
  const int m = tid & 127;

  // ---- opening (W0T global, coalesced: m per-lane) ----
  float acc = sB0[m];
  #pragma unroll
  for (int k = 0; k < 32; ++k)
    acc += gW0T[k*132 + m] * sXC[e*32 + k];
  const float to = tanhf(acc);
  sU[e*128 + m] = adtanh(acc);
  __syncthreads();

  // ---- forward layers (WT global, coalesced) ----
  for (int i0 = 0; i0 < 3; ++i0){
    const float* wl = gWT + i0*144*132;
    float p = sBS[i0*128 + m];
    #pragma unroll 8
    for (int k = 0; k < 128; ++k)
      p += wl[k*132 + m] * sU[e*128 + k];
    #pragma unroll
    for (int k = 0; k < 16; ++k)
      p += wl[(128+k)*132 + m] * sXC[e*32 + 16 + k];
    __syncthreads();   // all reads of sU done before update
    sU[e*128 + m] += HHC * adtanh(p);
    sTP[(i0*4 + e)*128 + m] = tanhf(p);
    __syncthreads();
  }

  // ---- z3: read ORIGINAL Ws layout (Ws[a][m], m per-lane -> coalesced) ----
  {
    const float* W2 = Wsg + 2*128*144;
    float zz = 0.0f;
    #pragma unroll 8
    for (int a = 0; a < 128; ++a)
      zz += W2[a*144 + m] * sTP[(8 + e)*128 + a] * sWW[a];
    sZ3[e*128 + m] = sWW[m] + HHC*zz;
  }
  __syncthreads();

  // ---- z2 ----
  {
    const float* W1 = Wsg + 1*128*144;
    float zz = 0.0f;
    #pragma unroll 8
    for (int a = 0; a < 128; ++a)
      zz += W1[a*144 + m] * sTP[(4 + e)*128 + a] * sZ3[e*128 + a];
    sZ2[e*128 + m] = sZ3[e*128 + m] + HHC*zz;
  }
  __syncthreads();

  // ---- z1 ----
  float z1;
  {
    const float* W0l = Wsg;
    float zz = 0.0f;
    #pragma unroll 8
    for (int a = 0; a < 128; ++a)
      zz += W0l[a*144 + m] * sTP[e*128 + a] * sZ2[e*128 + a];
    z1 = sZ2[e*128 + m] + HHC*zz;
  }
  const float s20 = (1.0f - to*to) * z1 * sK2[m];
  sJAC[(e*128 + m)*20] = to * z1;    // s1 scratch in jac col 0
  __syncthreads();

  // ---- grad output (reads original W0: W0[mm][gd]) ----
  if (tid < 64){
    int ge = tid >> 4, gd = tid & 15;
    float g = sCW[gd];
    #pragma unroll
    for (int j = 0; j < 16; ++j) g += sSA[gd*16 + j] * sXC[ge*32 + j];
    for (int mm = 0; mm < 128; ++mm)
      g += W0g[mm*32 + gd] * sJAC[(ge*128 + mm)*20];
    out[(size_t)(ebase + ge)*16 + gd] = g;
  }
  // ---- trH z1-part reduction (wave w covers half of example w>>1) ----
  {
    float r = s20;
    #pragma unroll
    for (int off = 32; off >= 1; off >>= 1) r += __shfl_xor(r, off, 64);
    if ((tid & 63) == 0){
      int w = tid >> 6;
      sTRHP[(w >> 1)*2 + (w & 1)] = r;
    }
  }
  __syncthreads();

  // ---- Jac init (W0T global, m per-lane coalesced) ----
  #pragma unroll
  for (int d = 0; d < 20; ++d)
    sJAC[(e*128 + m)*20 + d] = ((d < 15) ? gW0T[d*132 + m] : 0.0f) * to;
  __syncthreads();

  // ---- Jac propagation (hot loop): 2 waves per example ----
  const int w  = tid >> 6;         // 0..7
  const int je = w >> 1;           // 0..3
  const int a  = (w & 1)*64 + (tid & 63);   // row 0..127
  const float* jb = sJAC + je*2560;
  float trh = 0.0f;
  for (int i0 = 0; i0 < 3; ++i0){
    const float* wl = gWT + i0*144*132;
    float kj[16];
    #pragma unroll
    for (int d = 0; d < 16; ++d) kj[d] = 0.0f;
    #pragma unroll 4
    for (int b = 0; b < 128; ++b){
      float jv[16];
      { float4 t = *(const float4*)(jb + b*20 + 0);  jv[0]=t.x; jv[1]=t.y; jv[2]=t.z; jv[3]=t.w; }
      { float4 t = *(const float4*)(jb + b*20 + 4);  jv[4]=t.x; jv[5]=t.y; jv[6]=t.z; jv[7]=t.w; }
      { float4 t = *(const float4*)(jb + b*20 + 8);  jv[8]=t.x; jv[9]=t.y; jv[10]=t.z; jv[11]=t.w; }
      { float4 t = *(const float4*)(jb + b*20 + 12); jv[12]=t.x; jv[13]=t.y; jv[14]=t.z; jv[15]=t.w; }
      float wv = wl[b*132 + a];
      #pragma unroll
      for (int d = 0; d < 16; ++d) kj[d] += wv*jv[d];
    }
    float term;
    if (i0 == 0)      term = sZ2[je*128 + a];
    else if (i0 == 1) term = sZ3[je*128 + a];
    else              term = sWW[a];
    float tp = sTP[(i0*4 + je)*128 + a];
    float q = 0.0f;
    #pragma unroll
    for (int d = 0; d < 16; ++d) q += kj[d]*kj[d];
    float ss = (1.0f - tp*tp)*term*q;
    #pragma unroll
    for (int off = 32; off >= 1; off >>= 1) ss += __shfl_xor(ss, off, 64);
    trh += HHC * ss;
    __syncthreads();   // all jac reads done before update
    #pragma unroll
    for (int d = 0; d < 16; ++d)
      sJAC[(je*128 + a)*20 + d] += HHC*tp*kj[d];
    __syncthreads();
  }
  if ((tid & 63) == 0) sJP[w] = trh;
  __syncthreads();
  if (tid < 4){
    out[(size_t)NEX*16 + ebase + tid] =
      sTRHP[tid*2] + sTRHP[tid*2+1] + sJP[tid*2] + sJP[tid*2+1] + sTRA[0];
  }
}

extern "C" void kernel_launch(void* const* d_in, const int* in_sizes, int n_in,
                              void* d_out, int out_size, void* d_ws, size_t ws_size,
                              hipStream_t stream){
  const float* x   = (const float*)d_in[0];
  const float* ctx = (const float*)d_in[1];
  const float* W0  = (const float*)d_in[2];
  const float* b0  = (const float*)d_in[3];
  const float* Ws  = (const float*)d_in[4];
  const float* bs  = (const float*)d_in[5];
  const float* A   = (const float*)d_in[6];
  const float* cw  = (const float*)d_in[7];
  const float* ww  = (const float*)d_in[8];
  float* out = (float*)d_out;
  char* ws = (char*)d_ws;

  (void)in_sizes; (void)n_in; (void)out_size; (void)ws_size;
  hipFuncSetAttribute((const void*)phi_main,
                      hipFuncAttributeMaxDynamicSharedMemorySize, SM_TOTAL);
  phi_prep<<<1, NT, 0, stream>>>(W0, Ws, A, ws);
  phi_main<<<NEX/EPB, NT, SM_TOTAL, stream>>>(x, ctx, W0, b0, Ws, bs, cw, ww, ws, out);
}

// Round 9
// 1375.608 us; speedup vs baseline: 4.3981x; 1.9342x over previous
//
#include <hip/hip_runtime.h>

#define NEX 65536
#define NT 512
#define EPB 4          // examples per block
#define HHC (1.0f/3.0f)

typedef __attribute__((ext_vector_type(8))) short bf16x8;   // 8 bf16 = 4 VGPRs
typedef __attribute__((ext_vector_type(4))) float f32x4;

// ---- d_ws layout (bytes) ----
// WT : 3 layers transposed Ws f32 [144 k][132 m] (fwd loops, coalesced)
// W0T: [32][132] f32 (opening)
// WF : MFMA W fragments bf16 [3][mt=8][kt=4][hl=2][lane=64][j=8]
constexpr int WS_WT  = 0;                    // 228096
constexpr int WS_W0T = 228096;               // 16896
constexpr int WS_K2  = WS_W0T + 16896;       // 244992
constexpr int WS_SA  = WS_K2 + 512;          // 245504
constexpr int WS_TRA = WS_SA + 1024;         // 246528
constexpr int WS_WF  = 246784;               // 196608 -> total 443392

// ---- LDS layout (bytes) ----
constexpr int SM_JT  = 0;                    // J bf16 [hl=2][e=4][d=16][b=128] = 32768
constexpr int SM_TP  = 32768;                // tanh(pre) f32 [3][4][128] = 6144
constexpr int SM_U   = 38912;                // [4][128] f32
constexpr int SM_Z2  = 40960;
constexpr int SM_Z3  = 43008;
constexpr int SM_TO  = 45056;                // tanh(opening) [4][128]
constexpr int SM_S1  = 47104;                // to*z1 [4][128]
constexpr int SM_XC  = 49152;                // [4][32]
constexpr int SM_K2  = 49664;
constexpr int SM_B0  = 50176;
constexpr int SM_BS  = 50688;                // [3][128]
constexpr int SM_WW  = 52224;
constexpr int SM_CW  = 52736;
constexpr int SM_SA  = 52800;                // [16][16]
constexpr int SM_TRHP= 53824;                // [4][2]
constexpr int SM_JP  = 53856;                // [8 waves][4 e]
constexpr int SM_TRA = 53984;
constexpr int SM_TOTAL = 54000;              // 2 blocks/CU

__device__ __forceinline__ float bf2f(unsigned short u){
  union { unsigned int i; float f; } c; c.i = ((unsigned int)u) << 16; return c.f;
}
__device__ __forceinline__ unsigned short f2bf(float f){
  union { float f; unsigned int i; } c; c.f = f;
  unsigned int r = (c.i + 0x7FFFu + ((c.i >> 16) & 1u)) >> 16;
  return (unsigned short)r;
}
__device__ __forceinline__ float adtanh(float v){
  float a = fabsf(v);
  return a + log1pf(expf(-2.0f * a));
}

__global__ void phi_prep(const float* __restrict__ W0, const float* __restrict__ Ws,
                         const float* __restrict__ A, char* __restrict__ ws){
  const int tid = threadIdx.x;
  float* wt  = (float*)(ws + WS_WT);
  float* w0t = (float*)(ws + WS_W0T);
  float* k2  = (float*)(ws + WS_K2);
  float* sa  = (float*)(ws + WS_SA);
  float* trA = (float*)(ws + WS_TRA);
  unsigned short* wf = (unsigned short*)(ws + WS_WF);
  for (int idx = tid; idx < 3*144*132; idx += NT){
    int i = idx / (144*132), r = idx % (144*132);
    int k = r / 132, mm = r % 132;
    wt[idx] = (mm < 128) ? Ws[i*128*144 + mm*144 + k] : 0.0f;
  }
  for (int idx = tid; idx < 32*132; idx += NT){
    int k = idx / 132, mm = idx % 132;
    w0t[idx] = (mm < 128) ? W0[mm*32 + k] : 0.0f;
  }
  // MFMA fragments of Ws[i0][:, :128]: A[a][k], lane l holds row (l&15), k = kt*32+8*(l>>4)+j
  for (int idx = tid; idx < 3*8*4*64*8; idx += NT){
    int j  = idx & 7;
    int l  = (idx >> 3) & 63;
    int kt = (idx >> 9) & 3;
    int mt = (idx >> 11) & 7;
    int i0 = idx >> 14;
    int a  = mt*16 + (l & 15);
    int k  = kt*32 + 8*(l >> 4) + j;
    float w = Ws[i0*128*144 + a*144 + k];
    unsigned short hi = f2bf(w);
    unsigned short lo = f2bf(w - bf2f(hi));
    int base = ((((i0*8 + mt)*4 + kt)*2)*64 + l)*8 + j;
    wf[base]        = hi;          // hl=0
    wf[base + 512]  = lo;          // hl=1 (+64*8)
  }
  if (tid < 128){
    float s = 0.0f;
    for (int d = 0; d < 15; ++d){ float w = W0[tid*32 + d]; s += w*w; }
    k2[tid] = s;
  }
  if (tid >= 256 && tid < 512){   // symA = A^T A, 16x16
    int t = tid - 256; int i = t >> 4, j = t & 15;
    float s = 0.0f;
    for (int r = 0; r < 10; ++r) s += A[r*16 + i] * A[r*16 + j];
    sa[i*16 + j] = s;
  }
  if (tid == 255){
    float s = 0.0f;
    for (int d = 0; d < 15; ++d)
      for (int r = 0; r < 10; ++r){ float a = A[r*16 + d]; s += a*a; }
    trA[0] = s;
  }
}

__global__ void __launch_bounds__(NT, 4)
phi_main(const float* __restrict__ x, const float* __restrict__ ctx,
         const float* __restrict__ W0g, const float* __restrict__ b0,
         const float* __restrict__ Wsg, const float* __restrict__ bs,
         const float* __restrict__ cw, const float* __restrict__ ww,
         const char* __restrict__ ws, float* __restrict__ out){
  extern __shared__ char smem[];
  char*  jtB  = smem + SM_JT;
  float* sTP  = (float*)(smem + SM_TP);
  float* sU   = (float*)(smem + SM_U);
  float* sZ2  = (float*)(smem + SM_Z2);
  float* sZ3  = (float*)(smem + SM_Z3);
  float* sTO  = (float*)(smem + SM_TO);
  float* sS1  = (float*)(smem + SM_S1);
  float* sXC  = (float*)(smem + SM_XC);
  float* sK2  = (float*)(smem + SM_K2);
  float* sB0  = (float*)(smem + SM_B0);
  float* sBS  = (float*)(smem + SM_BS);
  float* sWW  = (float*)(smem + SM_WW);
  float* sCW  = (float*)(smem + SM_CW);
  float* sSA  = (float*)(smem + SM_SA);
  float* sTRHP= (float*)(smem + SM_TRHP);
  float* sJP  = (float*)(smem + SM_JP);
  float* sTRA = (float*)(smem + SM_TRA);

  const float* gWT  = (const float*)(ws + WS_WT);
  const float* gW0T = (const float*)(ws + WS_W0T);
  const unsigned short* wfL = (const unsigned short*)(ws + WS_WF);

  const int tid = threadIdx.x;
  const int ebase = blockIdx.x * EPB;

  // ---- stage small constants + inputs ----
  {
    if (tid < 128){
      sK2[tid] = ((const float*)(ws + WS_K2))[tid];
      sB0[tid] = b0[tid];
      sWW[tid] = ww[tid];
    }
    if (tid >= 128 && tid < 144) sCW[tid-128] = cw[tid-128];
    if (tid == 144) sTRA[0] = ((const float*)(ws + WS_TRA))[0];
    if (tid < 384) sBS[tid] = bs[tid];
    if (tid >= 256) sSA[tid-256] = ((const float*)(ws + WS_SA))[tid-256];
    if (tid < 128){
      int e = tid >> 5, k = tid & 31;
      int n = ebase + e;
      sXC[e*32 + k] = (k < 16) ? x[n*16 + k] : ctx[n*16 + (k-16)];
    }
  }
  __syncthreads();

  const int e = tid >> 7;          // 0..3
  const int m = tid & 127;

  // ---- opening ----
  float acc = sB0[m];
  #pragma unroll
  for (int k = 0; k < 32; ++k)
    acc += gW0T[k*132 + m] * sXC[e*32 + k];
  const float to = tanhf(acc);
  sTO[e*128 + m] = to;
  sU[e*128 + m] = adtanh(acc);
  __syncthreads();

  // ---- forward layers ----
  for (int i0 = 0; i0 < 3; ++i0){
    const float* wl = gWT + i0*144*132;
    float p = sBS[i0*128 + m];
    #pragma unroll 8
    for (int k = 0; k < 128; ++k)
      p += wl[k*132 + m] * sU[e*128 + k];
    #pragma unroll
    for (int k = 0; k < 16; ++k)
      p += wl[(128+k)*132 + m] * sXC[e*32 + 16 + k];
    __syncthreads();
    sU[e*128 + m] += HHC * adtanh(p);
    sTP[(i0*4 + e)*128 + m] = tanhf(p);
    __syncthreads();
  }

  // ---- z3 / z2 / z1 (original Ws layout, coalesced) ----
  {
    const float* W2 = Wsg + 2*128*144;
    float zz = 0.0f;
    #pragma unroll 8
    for (int a = 0; a < 128; ++a)
      zz += W2[a*144 + m] * sTP[(8 + e)*128 + a] * sWW[a];
    sZ3[e*128 + m] = sWW[m] + HHC*zz;
  }
  __syncthreads();
  {
    const float* W1 = Wsg + 1*128*144;
    float zz = 0.0f;
    #pragma unroll 8
    for (int a = 0; a < 128; ++a)
      zz += W1[a*144 + m] * sTP[(4 + e)*128 + a] * sZ3[e*128 + a];
    sZ2[e*128 + m] = sZ3[e*128 + m] + HHC*zz;
  }
  __syncthreads();
  float z1;
  {
    float zz = 0.0f;
    #pragma unroll 8
    for (int a = 0; a < 128; ++a)
      zz += Wsg[a*144 + m] * sTP[e*128 + a] * sZ2[e*128 + a];
    z1 = sZ2[e*128 + m] + HHC*zz;
  }
  const float s20 = (1.0f - to*to) * z1 * sK2[m];
  sS1[e*128 + m] = to * z1;
  __syncthreads();

  // ---- grad output ----
  if (tid < 64){
    int ge = tid >> 4, gd = tid & 15;
    float g = sCW[gd];
    #pragma unroll
    for (int j = 0; j < 16; ++j) g += sSA[gd*16 + j] * sXC[ge*32 + j];
    for (int mm = 0; mm < 128; ++mm)
      g += W0g[mm*32 + gd] * sS1[ge*128 + mm];
    out[(size_t)(ebase + ge)*16 + gd] = g;
  }
  // ---- trH z1-part reduction ----
  {
    float r = s20;
    #pragma unroll
    for (int off = 32; off >= 1; off >>= 1) r += __shfl_xor(r, off, 64);
    if ((tid & 63) == 0){
      int w = tid >> 6;
      sTRHP[(w >> 1)*2 + (w & 1)] = r;
    }
  }

  // ================= MFMA Jac propagation =================
  // wave = M-tile mt; lane: dcol = lane&15 (J/KJ column), lq = lane>>4;
  // lane owns rows a = mt*16 + lq*4 + r (r=0..3) for all 4 examples.
  const int lane = tid & 63;
  const int mt   = tid >> 6;
  const int lq   = lane >> 4;
  const int dcol = lane & 15;
  const int sw   = (dcol & 7) << 4;            // LDS XOR swizzle (both sides)

  float Jm[4][4];                               // [e][r] f32 master
  {
    float w0r[4];
    #pragma unroll
    for (int r = 0; r < 4; ++r){
      int aa = mt*16 + lq*4 + r;
      w0r[r] = (dcol < 15) ? W0g[aa*32 + dcol] : 0.0f;
    }
    #pragma unroll
    for (int ee = 0; ee < 4; ++ee){
      #pragma unroll
      for (int r = 0; r < 4; ++r)
        Jm[ee][r] = w0r[r] * sTO[ee*128 + mt*16 + lq*4 + r];
    }
  }

  auto writeJt = [&](){
    const int co = (mt*32 + lq*8) ^ sw;        // byte col within 256B row
    #pragma unroll
    for (int ee = 0; ee < 4; ++ee){
      unsigned int h0, h1, l0, l1;
      {
        unsigned short a0 = f2bf(Jm[ee][0]); unsigned short b0_ = f2bf(Jm[ee][0] - bf2f(a0));
        unsigned short a1 = f2bf(Jm[ee][1]); unsigned short b1_ = f2bf(Jm[ee][1] - bf2f(a1));
        unsigned short a2 = f2bf(Jm[ee][2]); unsigned short b2_ = f2bf(Jm[ee][2] - bf2f(a2));
        unsigned short a3 = f2bf(Jm[ee][3]); unsigned short b3_ = f2bf(Jm[ee][3] - bf2f(a3));
        h0 = (unsigned)a0 | ((unsigned)a1 << 16);
        h1 = (unsigned)a2 | ((unsigned)a3 << 16);
        l0 = (unsigned)b0_ | ((unsigned)b1_ << 16);
        l1 = (unsigned)b2_ | ((unsigned)b3_ << 16);
      }
      uint2 ph = { h0, h1 }, pl = { l0, l1 };
      *(uint2*)(jtB +         ee*4096 + dcol*256 + co) = ph;   // hi plane
      *(uint2*)(jtB + 16384 + ee*4096 + dcol*256 + co) = pl;   // lo plane
    }
  };
  writeJt();

  float trh[4] = {0.0f, 0.0f, 0.0f, 0.0f};
  #pragma unroll
  for (int i0 = 0; i0 < 3; ++i0){
    __syncthreads();                            // Jt writes visible
    f32x4 kacc[4] = {{0,0,0,0},{0,0,0,0},{0,0,0,0},{0,0,0,0}};
    const unsigned short* wfp = wfL + (size_t)(i0*8 + mt)*4096;  // [kt][hl][64][8]
    #pragma unroll
    for (int kt = 0; kt < 4; ++kt){
      bf16x8 ahi = *(const bf16x8*)(wfp + (kt*1024) + lane*8);
      bf16x8 alo = *(const bf16x8*)(wfp + (kt*1024) + 512 + lane*8);
      const int ro = dcol*256 + ((kt*64 + lq*16) ^ sw);
      #pragma unroll
      for (int ee = 0; ee < 4; ++ee){
        bf16x8 bhi = *(const bf16x8*)(jtB +         ee*4096 + ro);
        bf16x8 blo = *(const bf16x8*)(jtB + 16384 + ee*4096 + ro);
        kacc[ee] = __builtin_amdgcn_mfma_f32_16x16x32_bf16(ahi, bhi, kacc[ee], 0, 0, 0);
        kacc[ee] = __builtin_amdgcn_mfma_f32_16x16x32_bf16(ahi, blo, kacc[ee], 0, 0, 0);
        kacc[ee] = __builtin_amdgcn_mfma_f32_16x16x32_bf16(alo, bhi, kacc[ee], 0, 0, 0);
      }
    }
    // trH contribution + J update (registers + scalar LDS reads)
    #pragma unroll
    for (int ee = 0; ee < 4; ++ee){
      #pragma unroll
      for (int r = 0; r < 4; ++r){
        const int aa = mt*16 + lq*4 + r;
        float tp = sTP[(i0*4 + ee)*128 + aa];
        float term = (i0 == 0) ? sZ2[ee*128 + aa]
                   : (i0 == 1) ? sZ3[ee*128 + aa]
                               : sWW[aa];
        float kj = kacc[ee][r];
        trh[ee] += (1.0f - tp*tp) * term * kj * kj;
        Jm[ee][r] += HHC * tp * kj;
      }
    }
    if (i0 < 2){
      __syncthreads();                          // all Jt reads done before overwrite
      writeJt();
    }
  }

  // reduce trh across the wave, then across waves
  #pragma unroll
  for (int ee = 0; ee < 4; ++ee){
    float v = trh[ee];
    #pragma unroll
    for (int off = 32; off >= 1; off >>= 1) v += __shfl_xor(v, off, 64);
    if (lane == 0) sJP[mt*4 + ee] = v;
  }
  __syncthreads();
  if (tid < 4){
    float t = sTRHP[tid*2] + sTRHP[tid*2+1] + sTRA[0];
    #pragma unroll
    for (int w2 = 0; w2 < 8; ++w2) t += HHC * sJP[w2*4 + tid];
    out[(size_t)NEX*16 + ebase + tid] = t;
  }
}

extern "C" void kernel_launch(void* const* d_in, const int* in_sizes, int n_in,
                              void* d_out, int out_size, void* d_ws, size_t ws_size,
                              hipStream_t stream){
  const float* x   = (const float*)d_in[0];
  const float* ctx = (const float*)d_in[1];
  const float* W0  = (const float*)d_in[2];
  const float* b0  = (const float*)d_in[3];
  const float* Ws  = (const float*)d_in[4];
  const float* bs  = (const float*)d_in[5];
  const float* A   = (const float*)d_in[6];
  const float* cw  = (const float*)d_in[7];
  const float* ww  = (const float*)d_in[8];
  float* out = (float*)d_out;
  char* ws = (char*)d_ws;

  (void)in_sizes; (void)n_in; (void)out_size; (void)ws_size;
  hipFuncSetAttribute((const void*)phi_main,
                      hipFuncAttributeMaxDynamicSharedMemorySize, SM_TOTAL);
  phi_prep<<<1, NT, 0, stream>>>(W0, Ws, A, ws);
  phi_main<<<NEX/EPB, NT, SM_TOTAL, stream>>>(x, ctx, W0, b0, Ws, bs, cw, ww, ws, out);
}